// Round 12
// baseline (283.734 us; speedup 1.0000x reference)
//
#include <hip/hip_runtime.h>

namespace {

constexpr int BB = 2048;   // batch
constexpr int TT = 256;    // time steps
constexpr float L2E = 1.4426950408889634f;  // log2(e)

typedef __attribute__((ext_vector_type(8))) short bf8;          // 8 bf16 (4 VGPR)
typedef __attribute__((ext_vector_type(4))) float f4;           // MFMA acc
typedef __attribute__((ext_vector_type(2))) unsigned int u32x2;

#define MFMA16(a, b, c) __builtin_amdgcn_mfma_f32_16x16x32_bf16((a), (b), (c), 0, 0, 0)

__device__ __forceinline__ unsigned short f2bf_rne(float f) {
  unsigned int x = __float_as_uint(f);
  return (unsigned short)((x + 0x7fffu + ((x >> 16) & 1u)) >> 16);
}
__device__ __forceinline__ void mk_hilo(float v, short& hi, short& lo) {
  unsigned int u = __float_as_uint(v);
  hi = (short)(u >> 16);
  float r = v - __uint_as_float(u & 0xffff0000u);
  lo = (short)(__float_as_uint(r) >> 16);
}

// ============ all 4 GRU layers, LOCKSTEP-pipelined in one block ============
// 1024 threads = 16 waves = 4 quads; quad g = layer g, at step t = slot - g.
// ONE __syncthreads() per slot replaces R11's 3 LDS-counter polls + 4 atomics
// (each poll cost a ~120cy dependent ds_read per iteration in all 16 waves).
// h-state ring of 4 slots per layer, fragment-major [u>>3][n][u&7] (conflict-
// free b128). Ring serves self h-feedback (own slot t&3) and next layer's x
// (slot (t+1)&3). Slot indices (s-g)&3 are handled by 4-entry pointer tables
// indexed by the unroll literal -> pure register selects, no dynamic indexing.
// Hazards: peer/producer RAW 1 barrier apart; WAR 3 barriers apart. vmcnt at
// barrier is benign: only steady-state global op is layer-0's L2-resident x
// prefetch issued a full slot ahead. Gates pre-scaled by log2e (R,Z) / 2log2e
// (N) -> raw v_exp_f32; R/Z share one reciprocal.
__global__ __launch_bounds__(1024, 4) void gru_all(
    const float* __restrict__ xs, const float* __restrict__ xp,
    const float* __restrict__ W0s, const float* __restrict__ W0p,
    const float* __restrict__ Wihs, const float* __restrict__ Wihp,  // [3][192][64]
    const float* __restrict__ Whhs, const float* __restrict__ Whhp,  // [4][192][64]
    const float* __restrict__ bihs, const float* __restrict__ bihp,  // [4][192]
    const float* __restrict__ bhhs, const float* __restrict__ bhhp,
    float* __restrict__ hlast) {
  const int tid = threadIdx.x;
  const int Wv = tid >> 6, lane = tid & 63;
  const int g = Wv >> 2, w = Wv & 3;      // quad (=layer), wave-in-quad
  const int n15 = lane & 15, q = lane >> 4;
  const int blk = blockIdx.x, stack = blk >> 7;
  const int b0 = (blk & 127) * 16;

  const float* Wh = (stack ? Whhp : Whhs) + (size_t)g * 192 * 64;
  const float* bi = (stack ? bihp : bihs) + g * 192;
  const float* bh = (stack ? bhhp : bhhs) + g * 192;
  const float* Wx = (stack ? Wihp : Wihs) + (size_t)(g - 1) * 192 * 64;  // g>=1

  // [g][slot][frag=u>>3][n][elem=u&7]
  __shared__ unsigned short hb[4][4][8][16][8];

  for (int e = tid; e < 4 * 4 * 8 * 16 * 8; e += 1024)
    ((unsigned short*)hb)[e] = 0;

  const int mrow = 16 * w + n15;   // A-frag row; wave w owns Mtiles {w, w+4, w+8}
  const int mu = 16 * w + 4 * q;   // C-layout unit base for this lane's 4 regs
  const int fr_w = 2 * w + (q >> 1);  // write frag row
  const int eo_w = (q & 1) * 4;       // write elem offset

  // per-gate pre-scale: R,Z by log2e; N by 2*log2e
  const float gsc[3] = {L2E, L2E, 2.f * L2E};

  // ---- Wh fragments: rne bf16 of (scale * W) ----
  bf8 whh_[3][2];
  #pragma unroll
  for (int i = 0; i < 3; ++i) {
    #pragma unroll
    for (int kt = 0; kt < 2; ++kt) {
      const float* ph_ = Wh + (size_t)(i * 64 + mrow) * 64 + kt * 32 + q * 8;
      f4 ha = *(const f4*)ph_, hc = *(const f4*)(ph_ + 4);
      bf8 h2;
      #pragma unroll
      for (int j = 0; j < 8; ++j)
        h2[j] = (short)f2bf_rne(gsc[i] * ((j < 4) ? ha[j] : hc[j - 4]));
      whh_[i][kt] = h2;
    }
  }
  // ---- Wx fragments ----
  bf8 wxh_[3][2];
  if (g >= 1) {
    #pragma unroll
    for (int i = 0; i < 3; ++i) {
      #pragma unroll
      for (int kt = 0; kt < 2; ++kt) {
        const float* px_ = Wx + (size_t)(i * 64 + mrow) * 64 + kt * 32 + q * 8;
        f4 xa = *(const f4*)px_, xc = *(const f4*)(px_ + 4);
        bf8 h1;
        #pragma unroll
        for (int j = 0; j < 8; ++j)
          h1[j] = (short)f2bf_rne(gsc[i] * ((j < 4) ? xa[j] : xc[j - 4]));
        wxh_[i][kt] = h1;
      }
    }
  } else {
    // layer 0: scaled W0 trunc-hi/lo packed in one K=32 frag (see R6 comment).
    const float* W0 = stack ? W0p : W0s;
    #pragma unroll
    for (int i = 0; i < 3; ++i) {
      bf8 a;
      #pragma unroll
      for (int j = 0; j < 8; ++j) a[j] = 0;
      if (q == 0) {
        if (stack) {
          #pragma unroll
          for (int d = 0; d < 4; ++d) {
            short hi, lo;
            mk_hilo(gsc[i] * W0[(size_t)(i * 64 + mrow) * 4 + d], hi, lo);
            a[d] = hi; a[4 + d] = lo;
          }
        } else {
          short hi, lo; mk_hilo(gsc[i] * W0[i * 64 + mrow], hi, lo);
          a[0] = hi; a[1] = hi; a[4] = lo; a[5] = lo;
        }
      }
      wxh_[i][0] = a; wxh_[i][1] = a;
    }
  }

  f4 bR, bZ, bNx, bNh;
  #pragma unroll
  for (int r = 0; r < 4; ++r) {
    bR[r]  = L2E * (bi[mu + r] + bh[mu + r]);
    bZ[r]  = L2E * (bi[64 + mu + r] + bh[64 + mu + r]);
    bNx[r] = 2.f * L2E * bi[128 + mu + r];
    bNh[r] = 2.f * L2E * bh[128 + mu + r];
  }
  f4 h = {0.f, 0.f, 0.f, 0.f};

  // rotated ring-slot pointer tables (indexed only by unroll literal)
  const unsigned short* rs0[4];  // own h read, frag q (second frag = +512 elems)
  const unsigned short* rp0[4];  // producer y read, frag q
  unsigned short* ws0[4];        // own h write
  #pragma unroll
  for (int j = 0; j < 4; ++j) {
    const int s_self = (j - g) & 3;
    const int s_next = (j - g + 1) & 3;
    rs0[j] = &hb[g][s_self][q][n15][0];
    ws0[j] = &hb[g][s_next][fr_w][n15][eo_w];
    rp0[j] = &hb[(g >= 1 ? g - 1 : 0)][s_next][q][n15][0];
  }

  // layer-0 per-lane x prefetch (batch row b0+n15)
  const size_t xrow = (size_t)(b0 + n15);
  float px0 = 0.f, px1 = 0.f, px2 = 0.f, px3 = 0.f;
  if (g == 0) {
    if (stack) { f4 t4 = *(const f4*)(xp + xrow * TT * 4); px0 = t4[0]; px1 = t4[1]; px2 = t4[2]; px3 = t4[3]; }
    else       { px0 = xs[xrow * TT]; }
  }
  __syncthreads();

// One slot; S is the unroll literal. t = s + S - g; inactive quads just hit
// the barrier. All LDS addresses come from the precomputed tables.
#define GRU_BODY(S)                                                            \
  {                                                                            \
    const int tc = s + S - g;                                                  \
    if ((unsigned)tc < (unsigned)TT) {                                         \
      f4 aR = bR, aZ = bZ, aNx = bNx, aNh = bNh;                               \
      bf8 hh0 = *(const bf8*)rs0[S];                                           \
      bf8 hh1 = *(const bf8*)(rs0[S] + 512);                                   \
      if (g == 0) {                                                            \
        bf8 xq;                                                                \
        _Pragma("unroll") for (int j = 0; j < 8; ++j) xq[j] = 0;               \
        if (q == 0) {                                                          \
          if (stack) {                                                         \
            short a0 = (short)f2bf_rne(px0), a1 = (short)f2bf_rne(px1);        \
            short a2 = (short)f2bf_rne(px2), a3 = (short)f2bf_rne(px3);        \
            xq[0] = a0; xq[1] = a1; xq[2] = a2; xq[3] = a3;                    \
            xq[4] = a0; xq[5] = a1; xq[6] = a2; xq[7] = a3;                    \
          } else {                                                             \
            unsigned short xh = f2bf_rne(px0);                                 \
            float xf = __uint_as_float((unsigned)xh << 16);                    \
            unsigned short xl = f2bf_rne(px0 - xf);                            \
            xq[0] = (short)xh; xq[1] = (short)xl;                              \
            xq[4] = (short)xh; xq[5] = (short)xl;                              \
          }                                                                    \
        }                                                                      \
        __builtin_amdgcn_s_setprio(1);                                         \
        aR  = MFMA16(wxh_[0][0], xq, aR);                                      \
        aZ  = MFMA16(wxh_[1][0], xq, aZ);                                      \
        aNx = MFMA16(wxh_[2][0], xq, aNx);                                     \
        aR  = MFMA16(whh_[0][0], hh0, aR);  aR  = MFMA16(whh_[0][1], hh1, aR); \
        aZ  = MFMA16(whh_[1][0], hh0, aZ);  aZ  = MFMA16(whh_[1][1], hh1, aZ); \
        aNh = MFMA16(whh_[2][0], hh0, aNh); aNh = MFMA16(whh_[2][1], hh1, aNh);\
        __builtin_amdgcn_s_setprio(0);                                         \
        if (tc + 1 < TT) {                                                     \
          if (stack) { f4 t4 = *(const f4*)(xp + (xrow * TT + tc + 1) * 4);    \
                       px0 = t4[0]; px1 = t4[1]; px2 = t4[2]; px3 = t4[3]; }   \
          else       { px0 = xs[xrow * TT + tc + 1]; }                         \
        }                                                                      \
      } else {                                                                 \
        bf8 xc0 = *(const bf8*)rp0[S];                                         \
        bf8 xc1 = *(const bf8*)(rp0[S] + 512);                                 \
        __builtin_amdgcn_s_setprio(1);                                         \
        aR  = MFMA16(wxh_[0][0], xc0, aR);  aR  = MFMA16(wxh_[0][1], xc1, aR); \
        aZ  = MFMA16(wxh_[1][0], xc0, aZ);  aZ  = MFMA16(wxh_[1][1], xc1, aZ); \
        aNx = MFMA16(wxh_[2][0], xc0, aNx); aNx = MFMA16(wxh_[2][1], xc1, aNx);\
        aR  = MFMA16(whh_[0][0], hh0, aR);  aR  = MFMA16(whh_[0][1], hh1, aR); \
        aZ  = MFMA16(whh_[1][0], hh0, aZ);  aZ  = MFMA16(whh_[1][1], hh1, aZ); \
        aNh = MFMA16(whh_[2][0], hh0, aNh); aNh = MFMA16(whh_[2][1], hh1, aNh);\
        __builtin_amdgcn_s_setprio(0);                                         \
      }                                                                        \
      _Pragma("unroll") for (int r = 0; r < 4; ++r) {                          \
        float eR = __builtin_amdgcn_exp2f(-aR[r]);                             \
        float eZ = __builtin_amdgcn_exp2f(-aZ[r]);                             \
        float dR = 1.f + eR, dZ = 1.f + eZ;                                    \
        float qq = __builtin_amdgcn_rcpf(dR * dZ);                             \
        float rr = dZ * qq;   /* sigmoid(aR) */                                \
        float zz = dR * qq;   /* sigmoid(aZ) */                                \
        float eN = __builtin_amdgcn_exp2f(aNx[r] + rr * aNh[r]);               \
        float nn = 1.f - 2.f * __builtin_amdgcn_rcpf(eN + 1.f);                \
        h[r] = nn + zz * (h[r] - nn);                                          \
      }                                                                        \
      unsigned p01, p23;                                                       \
      asm("v_cvt_pk_bf16_f32 %0, %1, %2" : "=v"(p01) : "v"(h[0]), "v"(h[1])); \
      asm("v_cvt_pk_bf16_f32 %0, %1, %2" : "=v"(p23) : "v"(h[2]), "v"(h[3])); \
      u32x2 hiw = {p01, p23};                                                  \
      *(u32x2*)ws0[S] = hiw;                                                   \
      if (g == 3 && tc == TT - 1)                                              \
        *(f4*)&hlast[((size_t)stack * BB + b0 + n15) * 64 + mu] = h;           \
    }                                                                          \
    __syncthreads();                                                           \
  }

  for (int s = 0; s < TT + 4; s += 4) {
    GRU_BODY(0)
    GRU_BODY(1)
    GRU_BODY(2)
    GRU_BODY(3)
  }
#undef GRU_BODY
}

// ---------------- FC head ----------------
__global__ __launch_bounds__(128) void head(
    const float* __restrict__ hlast,
    const float* __restrict__ W1, const float* __restrict__ b1,
    const float* __restrict__ g1, const float* __restrict__ be1,
    const float* __restrict__ m1, const float* __restrict__ v1,
    const float* __restrict__ W2, const float* __restrict__ b2,
    const float* __restrict__ g2, const float* __restrict__ be2,
    const float* __restrict__ m2, const float* __restrict__ v2,
    const float* __restrict__ W3, const float* __restrict__ b3,
    float* __restrict__ out) {
  const int b = blockIdx.x;
  const int j = threadIdx.x;
  __shared__ float xin[128];
  __shared__ float y1[128];
  __shared__ float y2[128];
  xin[j] = (j < 64) ? hlast[(size_t)b * 64 + j]
                    : hlast[(size_t)BB * 64 + (size_t)b * 64 + (j - 64)];
  __syncthreads();
  float acc = b1[j];
  #pragma unroll 8
  for (int k = 0; k < 128; ++k) acc = fmaf(W1[j * 128 + k], xin[k], acc);
  float sc = g1[j] * rsqrtf(v1[j] + 1e-5f);
  y1[j] = fmaxf(0.f, (acc - m1[j]) * sc + be1[j]);
  __syncthreads();
  acc = b2[j];
  #pragma unroll 8
  for (int k = 0; k < 128; ++k) acc = fmaf(W2[j * 128 + k], y1[k], acc);
  sc = g2[j] * rsqrtf(v2[j] + 1e-5f);
  y2[j] = fmaxf(0.f, (acc - m2[j]) * sc + be2[j]);
  __syncthreads();
  if (j < 2) {
    float a = b3[j];
    #pragma unroll 8
    for (int k = 0; k < 128; ++k) a = fmaf(W3[j * 128 + k], y2[k], a);
    out[(size_t)b * 2 + j] = a;
  }
}

}  // namespace

extern "C" void kernel_launch(void* const* d_in, const int* in_sizes, int n_in,
                              void* d_out, int out_size, void* d_ws, size_t ws_size,
                              hipStream_t stream) {
  (void)in_sizes; (void)n_in; (void)out_size; (void)ws_size;
  const float* sent   = (const float*)d_in[0];
  const float* price  = (const float*)d_in[1];
  const float* s_Wih0 = (const float*)d_in[2];
  const float* s_Wih  = (const float*)d_in[3];
  const float* s_Whh  = (const float*)d_in[4];
  const float* s_bih  = (const float*)d_in[5];
  const float* s_bhh  = (const float*)d_in[6];
  const float* p_Wih0 = (const float*)d_in[7];
  const float* p_Wih  = (const float*)d_in[8];
  const float* p_Whh  = (const float*)d_in[9];
  const float* p_bih  = (const float*)d_in[10];
  const float* p_bhh  = (const float*)d_in[11];
  const float* fc1_W  = (const float*)d_in[12];
  const float* fc1_b  = (const float*)d_in[13];
  const float* bn1_g  = (const float*)d_in[14];
  const float* bn1_b  = (const float*)d_in[15];
  const float* bn1_m  = (const float*)d_in[16];
  const float* bn1_v  = (const float*)d_in[17];
  const float* fc2_W  = (const float*)d_in[18];
  const float* fc2_b  = (const float*)d_in[19];
  const float* bn2_g  = (const float*)d_in[20];
  const float* bn2_b  = (const float*)d_in[21];
  const float* bn2_m  = (const float*)d_in[22];
  const float* bn2_v  = (const float*)d_in[23];
  const float* fc3_W  = (const float*)d_in[24];
  const float* fc3_b  = (const float*)d_in[25];
  float* out = (float*)d_out;

  float* hlast = (float*)d_ws;  // [2, B, 64] f32

  gru_all<<<dim3(256), dim3(1024), 0, stream>>>(
      sent, price, s_Wih0, p_Wih0, s_Wih, p_Wih, s_Whh, p_Whh,
      s_bih, p_bih, s_bhh, p_bhh, hlast);

  head<<<dim3(BB), dim3(128), 0, stream>>>(
      hlast, fc1_W, fc1_b, bn1_g, bn1_b, bn1_m, bn1_v,
      fc2_W, fc2_b, bn2_g, bn2_b, bn2_m, bn2_v, fc3_W, fc3_b, out);
}